// Round 1
// baseline (116.072 us; speedup 1.0000x reference)
//
#include <hip/hip_runtime.h>

#define BB 4
#define CC 256
#define HH 56
#define WW 56
#define HW 3136          // 56*56
#define KK 7
#define GG 16
#define GC 16
#define CH 64            // C/4
#define KL 49            // K*K
#define PADW 3
#define TS 8             // spatial tile 8x8
#define XT 14            // TS + K - 1

// Kernel 1: h = relu(bn(w1 @ x)), h layout [B][CH][HW]
__global__ __launch_bounds__(128) void k1_conv1(
        const float* __restrict__ x, const float* __restrict__ w1,
        const float* __restrict__ gamma, const float* __restrict__ beta,
        const float* __restrict__ mean, const float* __restrict__ var,
        float* __restrict__ h) {
    int px = blockIdx.x * 128 + threadIdx.x;
    int og = blockIdx.y;            // 4 groups of 16 out-channels
    int b  = blockIdx.z;
    bool ok = px < HW;
    int pxc = ok ? px : 0;
    const float* xb = x + (size_t)b * CC * HW + pxc;
    int o0 = og * 16;
    const float* w1p = w1 + (size_t)o0 * CC;

    float acc[16];
#pragma unroll
    for (int i = 0; i < 16; i++) acc[i] = 0.f;

    for (int c = 0; c < CC; c += 4) {
        float xv0 = xb[(size_t)(c + 0) * HW];
        float xv1 = xb[(size_t)(c + 1) * HW];
        float xv2 = xb[(size_t)(c + 2) * HW];
        float xv3 = xb[(size_t)(c + 3) * HW];
#pragma unroll
        for (int i = 0; i < 16; i++) {
            // w1p index is block-uniform -> scalar loads
            acc[i] = fmaf(xv0, w1p[i * CC + c + 0], acc[i]);
            acc[i] = fmaf(xv1, w1p[i * CC + c + 1], acc[i]);
            acc[i] = fmaf(xv2, w1p[i * CC + c + 2], acc[i]);
            acc[i] = fmaf(xv3, w1p[i * CC + c + 3], acc[i]);
        }
    }
    if (ok) {
        float* hp = h + ((size_t)b * CH + o0) * HW + px;
#pragma unroll
        for (int i = 0; i < 16; i++) {
            int o = o0 + i;
            float sc = gamma[o] * rsqrtf(var[o] + 1e-5f);
            float sh = beta[o] - mean[o] * sc;
            float v = fmaf(acc[i], sc, sh);
            hp[(size_t)i * HW] = v > 0.f ? v : 0.f;
        }
    }
}

// Kernel 2: fused conv2 (weight generation) + involution.
// One block per (b, g, 8x8 tile). 256 threads.
__global__ __launch_bounds__(256) void k2_fused(
        const float* __restrict__ x, const float* __restrict__ h,
        const float* __restrict__ w2, const float* __restrict__ b2,
        float* __restrict__ out) {
    __shared__ float h_t[64][64];      // [c][px]   16 KB
    __shared__ float w2_t[64][64];     // [c][k]    16 KB (k padded to 64)
    __shared__ float wgt[KL][64];      // [k][px]   12.25 KB
    __shared__ float xp[GC][XT * XT];  // [gc][r*14+col] 12.25 KB

    int tx = blockIdx.x, ty = blockIdx.y;
    int b = blockIdx.z >> 4, g = blockIdx.z & 15;
    int gx = tx * TS, gy = ty * TS;
    int tid = threadIdx.x;

    // ---- Phase A: stage h tile (transposed to [c][px]) and w2 group ----
    const float* hb = h + (size_t)b * CH * HW;
#pragma unroll
    for (int l = 0; l < 16; l++) {
        int idx = tid + l * 256;       // 4096 values
        int c = idx >> 6, px = idx & 63;
        int py = px >> 3, pxx = px & 7;
        h_t[c][px] = hb[(size_t)c * HW + (gy + py) * WW + gx + pxx];
    }
    const float* w2g = w2 + (size_t)g * KL * CH;
#pragma unroll
    for (int l = 0; l < 16; l++) {
        int idx = tid + l * 256;       // 4096 slots, (c,k) order => linear LDS writes
        int c = idx >> 6, k = idx & 63;
        w2_t[c][k] = (k < KL) ? w2g[k * CH + c] : 0.f;
    }
    __syncthreads();

    // ---- Phase C (issue early): x patch loads into registers ----
    const float* xg = x + ((size_t)b * CC + g * GC) * HW;
    float xv[13];
#pragma unroll
    for (int l = 0; l < 13; l++) {
        int idx = tid + l * 256;
        float v = 0.f;
        if (idx < GC * XT * XT) {
            int c = idx / (XT * XT);
            int rr = idx % (XT * XT);
            int r = rr / XT, col = rr % XT;
            int y = gy + r - PADW, xc = gx + col - PADW;
            if (y >= 0 && y < HH && xc >= 0 && xc < WW)
                v = xg[(size_t)c * HW + y * WW + xc];
        }
        xv[l] = v;
    }

    // ---- Phase B: weight GEMM  wgt[k][px] = sum_c w2[k][c]*h[c][px] + b2 ----
    int kq = tid >> 4;     // 0..15 -> k = kq*4+kk
    int pq = tid & 15;     // px = pq*4+i
    float acc[4][4];
#pragma unroll
    for (int a = 0; a < 4; a++)
#pragma unroll
        for (int bcol = 0; bcol < 4; bcol++) acc[a][bcol] = 0.f;

    for (int c = 0; c < 64; c++) {
        float4 wv = *(const float4*)&w2_t[c][kq * 4];
        float4 hv = *(const float4*)&h_t[c][pq * 4];
        const float wa[4] = {wv.x, wv.y, wv.z, wv.w};
        const float ha[4] = {hv.x, hv.y, hv.z, hv.w};
#pragma unroll
        for (int kk = 0; kk < 4; kk++)
#pragma unroll
            for (int i = 0; i < 4; i++)
                acc[kk][i] = fmaf(wa[kk], ha[i], acc[kk][i]);
    }
#pragma unroll
    for (int kk = 0; kk < 4; kk++) {
        int k = kq * 4 + kk;
        if (k < KL) {
            float bias = b2[g * KL + k];
            float4 st = make_float4(acc[kk][0] + bias, acc[kk][1] + bias,
                                    acc[kk][2] + bias, acc[kk][3] + bias);
            *(float4*)&wgt[k][pq * 4] = st;
        }
    }
    // write x patch to LDS
#pragma unroll
    for (int l = 0; l < 13; l++) {
        int idx = tid + l * 256;
        if (idx < GC * XT * XT) ((float*)xp)[idx] = xv[l];
    }
    __syncthreads();

    // ---- Phase D: involution. thread -> (c, 4 consecutive px) ----
    int c = tid >> 4;          // 0..15 channel within group
    int pq2 = tid & 15;        // px = pq2*4 + i
    int py = pq2 >> 1;
    int x0 = (pq2 & 1) * 4;

    float o4[4] = {0.f, 0.f, 0.f, 0.f};
#pragma unroll
    for (int ky = 0; ky < KK; ky++) {
        float xr[10];
#pragma unroll
        for (int j = 0; j < 10; j++)
            xr[j] = xp[c][(py + ky) * XT + x0 + j];
#pragma unroll
        for (int kx = 0; kx < KK; kx++) {
            float4 wv = *(const float4*)&wgt[ky * KK + kx][pq2 * 4];
            o4[0] = fmaf(wv.x, xr[kx + 0], o4[0]);
            o4[1] = fmaf(wv.y, xr[kx + 1], o4[1]);
            o4[2] = fmaf(wv.z, xr[kx + 2], o4[2]);
            o4[3] = fmaf(wv.w, xr[kx + 3], o4[3]);
        }
    }
    float* op = out + ((size_t)b * CC + g * GC + c) * HW + (gy + py) * WW + gx + x0;
    *(float4*)op = make_float4(o4[0], o4[1], o4[2], o4[3]);
}

extern "C" void kernel_launch(void* const* d_in, const int* in_sizes, int n_in,
                              void* d_out, int out_size, void* d_ws, size_t ws_size,
                              hipStream_t stream) {
    const float* x     = (const float*)d_in[0];
    const float* w1    = (const float*)d_in[1];
    const float* gamma = (const float*)d_in[2];
    const float* beta  = (const float*)d_in[3];
    const float* mean  = (const float*)d_in[4];
    const float* var   = (const float*)d_in[5];
    const float* w2    = (const float*)d_in[6];
    const float* b2    = (const float*)d_in[7];
    float* out = (float*)d_out;
    float* h   = (float*)d_ws;   // [B][64][3136] fp32 = 3.2 MB

    k1_conv1<<<dim3((HW + 127) / 128, 4, BB), 128, 0, stream>>>(
        x, w1, gamma, beta, mean, var, h);
    k2_fused<<<dim3(7, 7, BB * GG), 256, 0, stream>>>(x, h, w2, b2, out);
}

// Round 3
// 55.502 us; speedup vs baseline: 2.0913x; 2.0913x over previous
//
#include <hip/hip_runtime.h>

typedef __attribute__((ext_vector_type(8))) short short8;
typedef __attribute__((ext_vector_type(4))) float f32x4;
typedef __attribute__((ext_vector_type(4))) unsigned int u32x4;

#define BB 4
#define HW 3136
#define NX (4*256*3136)          // total x elements
#define LDS_W2P 14336            // w2p offset (after h_t 112*128)
#define LDS_B2S 29696            // 64*116*4 wgt region end
#define LDS_TOT 29952

__device__ __forceinline__ unsigned int f2bf(float f) {
    unsigned int u = __float_as_uint(f);
    return (u + 0x7FFFu + ((u >> 16) & 1u)) >> 16;   // RNE to bf16 bits
}

// k0: w1t[c][o] = w1[o][c] * bn_scale[o];  bias_d[o] = beta - mean*scale
__global__ void k0_prep(const float* __restrict__ w1, const float* __restrict__ gamma,
                        const float* __restrict__ beta, const float* __restrict__ mean,
                        const float* __restrict__ var, float* __restrict__ w1t,
                        float* __restrict__ bias_d) {
    int idx = blockIdx.x * 256 + threadIdx.x;      // < 16384
    int o = idx & 63, c = idx >> 6;
    float sc = gamma[o] * rsqrtf(var[o] + 1e-5f);
    w1t[idx] = w1[o * 256 + c] * sc;
    if (idx < 64)
        bias_d[idx] = beta[idx] - mean[idx] * (gamma[idx] * rsqrtf(var[idx] + 1e-5f));
}

// k1: h = relu(conv1+bn), written bf16 as h_g[b][px][64c]
// grid 448 blocks: XCD-chunk swizzle so the 8 o-groups of a px-tile share an XCD.
__global__ __launch_bounds__(256) void k1_conv1(
        const float* __restrict__ x, const float* __restrict__ w1t,
        const float* __restrict__ bias_d, unsigned short* __restrict__ h_g) {
    int orig = blockIdx.x;
    int tile = (orig & 7) + 8 * (orig >> 6);   // tile%8 == orig%8 -> same XCD for all og
    if (tile >= 49) return;
    int og = (orig >> 3) & 7;
    int tid = threadIdx.x;
    int pf = tile * 256 + tid;                 // 0..12543 over (b,px)
    int b = pf / HW;
    int px = pf - b * HW;
    int o0 = og * 8;

    const float* xb = x + (size_t)b * 256 * HW + px;
    float acc[8];
#pragma unroll
    for (int i = 0; i < 8; i++) acc[i] = 0.f;

    for (int c = 0; c < 256; c += 8) {
        float xr[8];
#pragma unroll
        for (int u = 0; u < 8; u++) xr[u] = xb[(size_t)(c + u) * HW];
#pragma unroll
        for (int u = 0; u < 8; u++) {
            const float* wr = w1t + (c + u) * 64 + o0;   // block-uniform -> s_loads
#pragma unroll
            for (int i = 0; i < 8; i++) acc[i] = fmaf(xr[u], wr[i], acc[i]);
        }
    }
    unsigned int up[4];
#pragma unroll
    for (int i = 0; i < 4; i++) {
        float v0 = fmaxf(acc[2 * i] + bias_d[o0 + 2 * i], 0.f);
        float v1 = fmaxf(acc[2 * i + 1] + bias_d[o0 + 2 * i + 1], 0.f);
        up[i] = f2bf(v0) | (f2bf(v1) << 16);
    }
    u32x4 st = {up[0], up[1], up[2], up[3]};
    *(u32x4*)((char*)h_g + ((size_t)(b * HW + px) * 64 + o0) * 2) = st;
}

// k2: fused weight-GEMM (bf16 MFMA) + involution. Block = (2-row tile, g, b), 256 thr.
__global__ __launch_bounds__(256, 5) void k2_fused(
        const float* __restrict__ x, const unsigned short* __restrict__ h_g,
        const float* __restrict__ w2, const float* __restrict__ b2,
        float* __restrict__ out) {
    __shared__ __align__(16) char lds[LDS_TOT];
    int tile = blockIdx.x, g = blockIdx.y, b = blockIdx.z;
    int tid = threadIdx.x;

    // ---- Phase A1: stage h tile (112 px rows x 64c bf16), XOR-swizzled rows ----
    const char* hg = (const char*)h_g + ((size_t)b * HW + tile * 112) * 128;
    for (int i = tid; i < 896; i += 256) {          // 896 x 16B chunks
        int row = i >> 3, cb = (i & 7) << 4;
        u32x4 v = *(const u32x4*)(hg + row * 128 + cb);
        *(u32x4*)(lds + row * 128 + (cb ^ ((row & 7) << 4))) = v;
    }
    // ---- Phase A2: w2 group -> bf16, rows padded to 64 taps, swizzled ----
    {
        int k = tid >> 2, cg = tid & 3;
        unsigned int pk[8];
        if (k < 49) {
            const float* wr = w2 + ((size_t)(g * 49 + k)) * 64 + cg * 16;
#pragma unroll
            for (int i = 0; i < 8; i++)
                pk[i] = f2bf(wr[2 * i]) | (f2bf(wr[2 * i + 1]) << 16);
        } else {
#pragma unroll
            for (int i = 0; i < 8; i++) pk[i] = 0;
        }
#pragma unroll
        for (int hh = 0; hh < 2; hh++) {
            u32x4 v = {pk[hh * 4 + 0], pk[hh * 4 + 1], pk[hh * 4 + 2], pk[hh * 4 + 3]};
            *(u32x4*)(lds + LDS_W2P + k * 128 + ((cg * 32 + hh * 16) ^ ((k & 7) << 4))) = v;
        }
    }
    if (tid < 49) ((float*)(lds + LDS_B2S))[tid] = b2[g * 49 + tid];
    __syncthreads();

    // ---- Phase B: wgt[64tap][112px] = w2p(64x64) @ h(64c x 112px) via MFMA ----
    int lane = tid & 63, wid = tid >> 6;
    f32x4 acc[7];
#pragma unroll
    for (int n = 0; n < 7; n++) acc[n] = (f32x4){0.f, 0.f, 0.f, 0.f};
    int arow = wid * 16 + (lane & 15);
#pragma unroll
    for (int ks = 0; ks < 2; ks++) {
        int kc = ks * 64 + ((lane >> 4) << 4);       // byte col of 8 bf16 k-chunk
        short8 a = *(const short8*)(lds + LDS_W2P + arow * 128 + (kc ^ ((arow & 7) << 4)));
#pragma unroll
        for (int n = 0; n < 7; n++) {
            int brow = n * 16 + (lane & 15);
            short8 bb = *(const short8*)(lds + brow * 128 + (kc ^ ((brow & 7) << 4)));
            acc[n] = __builtin_amdgcn_mfma_f32_16x16x32_bf16(a, bb, acc[n], 0, 0, 0);
        }
    }
    __syncthreads();    // all B-reads done before overwriting h_t/w2p with wgt

    // ---- Epilogue: wgt fp32 [64][116] at lds+0 (aliases h_t/w2p), +bias ----
    {
        const float* b2s = (const float*)(lds + LDS_B2S);
#pragma unroll
        for (int n = 0; n < 7; n++) {
#pragma unroll
            for (int r = 0; r < 4; r++) {
                int tap = wid * 16 + ((lane >> 4) << 2) + r;
                if (tap < 49) {
                    int px = n * 16 + (lane & 15);
                    ((float*)lds)[tap * 116 + px] = acc[n][r] + b2s[tap];
                }
            }
        }
    }
    __syncthreads();

    // ---- Phase D: involution. thread = (2 channels, 4 contiguous px) ----
    int cq = tid >> 5, pg = tid & 31;
    if (pg < 28) {
        int py = (pg >= 14) ? 1 : 0;
        int x0 = (pg - 14 * py) * 4;               // col of first px in row
        int c0 = g * 16 + cq * 2;
        int rowb = tile * 2 + py;
        float accd[2][4] = {{0.f, 0.f, 0.f, 0.f}, {0.f, 0.f, 0.f, 0.f}};
        for (int ky = 0; ky < 7; ky++) {
            int rr = rowb + ky - 3;
            if (rr < 0 || rr >= 56) continue;      // zero-pad rows contribute 0
            float w[2][12];
#pragma unroll
            for (int cc = 0; cc < 2; cc++) {
                int base = (b * 256 + c0 + cc) * HW + rr * 56 + x0 - 4;
#pragma unroll
                for (int k3 = 0; k3 < 3; k3++) {
                    int o = base + k3 * 4;
                    o = min(max(o, 0), NX - 4);    // clamp: OOB values get zeroed below
                    *(f32x4*)&w[cc][k3 * 4] = *(const f32x4*)(x + o);
                }
            }
            if (x0 == 0) {                          // img cols < 0
                w[0][1] = w[0][2] = w[0][3] = 0.f;
                w[1][1] = w[1][2] = w[1][3] = 0.f;
            }
            if (x0 == 52) {                         // img cols > 55
                w[0][8] = w[0][9] = w[0][10] = 0.f;
                w[1][8] = w[1][9] = w[1][10] = 0.f;
            }
#pragma unroll
            for (int kx = 0; kx < 7; kx++) {
                f32x4 wg = *(const f32x4*)(lds + ((ky * 7 + kx) * 116 + py * 56 + x0) * 4);
#pragma unroll
                for (int cc = 0; cc < 2; cc++) {
#pragma unroll
                    for (int pi = 0; pi < 4; pi++)
                        accd[cc][pi] = fmaf(wg[pi], w[cc][pi + kx + 1], accd[cc][pi]);
                }
            }
        }
#pragma unroll
        for (int cc = 0; cc < 2; cc++) {
            f32x4 st = {accd[cc][0], accd[cc][1], accd[cc][2], accd[cc][3]};
            *(f32x4*)(out + (size_t)(b * 256 + c0 + cc) * HW + tile * 112 + pg * 4) = st;
        }
    }
}

extern "C" void kernel_launch(void* const* d_in, const int* in_sizes, int n_in,
                              void* d_out, int out_size, void* d_ws, size_t ws_size,
                              hipStream_t stream) {
    const float* x     = (const float*)d_in[0];
    const float* w1    = (const float*)d_in[1];
    const float* gamma = (const float*)d_in[2];
    const float* beta  = (const float*)d_in[3];
    const float* mean  = (const float*)d_in[4];
    const float* var   = (const float*)d_in[5];
    const float* w2    = (const float*)d_in[6];
    const float* b2    = (const float*)d_in[7];
    float* out = (float*)d_out;

    float* w1t    = (float*)d_ws;                                  // 64 KB
    float* bias_d = w1t + 16384;                                   // 256 B
    unsigned short* h_g = (unsigned short*)((char*)d_ws + 65792);  // 1.6 MB bf16

    k0_prep<<<64, 256, 0, stream>>>(w1, gamma, beta, mean, var, w1t, bias_d);
    k1_conv1<<<448, 256, 0, stream>>>(x, w1t, bias_d, h_g);
    k2_fused<<<dim3(28, 16, BB), 256, 0, stream>>>(x, h_g, w2, b2, out);
}

// Round 4
// 39.768 us; speedup vs baseline: 2.9188x; 1.3957x over previous
//
#include <hip/hip_runtime.h>

typedef __attribute__((ext_vector_type(8))) short short8;
typedef __attribute__((ext_vector_type(4))) float f32x4;
typedef __attribute__((ext_vector_type(4))) unsigned int u32x4;
typedef unsigned short ushort_t;

#define BB 4
#define HW 3136
#define NX (4*256*3136)          // total x elements
#define LDS_W2P 14336            // k2: w2p offset (after h_t 112*128)
#define LDS_B2S 29696            // k2: 64*116*4 wgt region end
#define LDS_TOT 29952

// k1 LDS regions
#define K1_XB0 32768
#define K1_XB1 36864
#define K1_BIAS 40960
#define K1_TOT 41216

__device__ __forceinline__ unsigned int f2bf(float f) {
    unsigned int u = __float_as_uint(f);
    return (u + 0x7FFFu + ((u >> 16) & 1u)) >> 16;   // RNE to bf16 bits
}

// k0: w1bf[o][c] = bf16(w1[o][c] * bn_scale[o]);  bias_d[o] = beta - mean*scale
__global__ void k0_prep(const float* __restrict__ w1, const float* __restrict__ gamma,
                        const float* __restrict__ beta, const float* __restrict__ mean,
                        const float* __restrict__ var, ushort_t* __restrict__ w1bf,
                        float* __restrict__ bias_d) {
    int idx = blockIdx.x * 256 + threadIdx.x;      // < 16384
    int o = idx >> 8;
    float sc = gamma[o] * rsqrtf(var[o] + 1e-5f);
    w1bf[idx] = (ushort_t)f2bf(w1[idx] * sc);
    if (idx < 64)
        bias_d[idx] = beta[idx] - mean[idx] * (gamma[idx] * rsqrtf(var[idx] + 1e-5f));
}

// k1: h = relu(conv1+bn) via bf16 MFMA. h_g[b][px][64c] bf16.
// Block = 56-px tile (row-aligned), 4 waves. M=56(pad64) N=64o K=256c.
__global__ __launch_bounds__(256) void k1_mfma(
        const float* __restrict__ x, const ushort_t* __restrict__ w1bf,
        const float* __restrict__ bias_d, ushort_t* __restrict__ h_g) {
    __shared__ __align__(16) char lds[K1_TOT];
    int blk = blockIdx.x;
    int tile = blk % 56, b = blk / 56;
    int px0 = tile * 56;
    int tid = threadIdx.x;
    int lane = tid & 63, w = tid >> 6;

    // ---- stage w1bf [64o][256c] bf16, rows 512B, XOR-swizzled ----
    for (int i = tid; i < 2048; i += 256) {        // 16B chunks
        int row = i >> 5, col = (i & 31) << 4;
        u32x4 v = *(const u32x4*)(w1bf + i * 8);
        *(u32x4*)(lds + (row << 9) + (col ^ ((row & 7) << 4))) = v;
    }
    if (tid < 64) ((float*)(lds + K1_BIAS))[tid] = bias_d[tid];

    // x staging helpers: thread -> (px = tid&63, cg = tid>>6), 8 c each
    int spx = tid & 63, scg = tid >> 6;
    int gpx = min(px0 + spx, HW - 1);              // clamp pad rows (garbage, masked later)
    const float* xbase = x + (size_t)b * 256 * HW + gpx;
    int sdst_off = spx * 64 + ((scg << 4) ^ ((spx & 3) << 4));

    float xr[8];
#pragma unroll
    for (int u = 0; u < 8; u++) xr[u] = xbase[(size_t)(scg * 8 + u) * HW];

    f32x4 acc[4];
#pragma unroll
    for (int n = 0; n < 4; n++) acc[n] = (f32x4){0.f, 0.f, 0.f, 0.f};

    // write step0
    {
        unsigned int pk[4];
#pragma unroll
        for (int j = 0; j < 4; j++)
            pk[j] = f2bf(xr[2 * j]) | (f2bf(xr[2 * j + 1]) << 16);
        u32x4 v = {pk[0], pk[1], pk[2], pk[3]};
        *(u32x4*)(lds + K1_XB0 + sdst_off) = v;
    }
    __syncthreads();

    int arow = w * 16 + (lane & 15);
    int a_off = arow * 64 + (((lane >> 4) << 4) ^ ((arow & 3) << 4));

    for (int ks = 0; ks < 8; ks++) {
        if (ks < 7) {
            const float* xp = xbase + (size_t)((ks + 1) * 32 + scg * 8) * HW;
#pragma unroll
            for (int u = 0; u < 8; u++) xr[u] = xp[(size_t)u * HW];
        }
        int xb = (ks & 1) ? K1_XB1 : K1_XB0;
        short8 a = *(const short8*)(lds + xb + a_off);
#pragma unroll
        for (int n = 0; n < 4; n++) {
            int brow = n * 16 + (lane & 15);
            short8 bb = *(const short8*)(lds + (brow << 9) +
                          ((ks * 64 + ((lane >> 4) << 4)) ^ ((brow & 7) << 4)));
            acc[n] = __builtin_amdgcn_mfma_f32_16x16x32_bf16(a, bb, acc[n], 0, 0, 0);
        }
        __syncthreads();
        if (ks < 7) {
            unsigned int pk[4];
#pragma unroll
            for (int j = 0; j < 4; j++)
                pk[j] = f2bf(xr[2 * j]) | (f2bf(xr[2 * j + 1]) << 16);
            u32x4 v = {pk[0], pk[1], pk[2], pk[3]};
            *(u32x4*)(lds + ((ks & 1) ? K1_XB0 : K1_XB1) + sdst_off) = v;
            __syncthreads();
        }
    }

    // epilogue: h_g[(b*HW+px)*64 + o] = relu(acc + bias)
#pragma unroll
    for (int n = 0; n < 4; n++) {
        int o = n * 16 + (lane & 15);
        float bo = ((const float*)(lds + K1_BIAS))[o];
#pragma unroll
        for (int r = 0; r < 4; r++) {
            int pxl = w * 16 + ((lane >> 4) << 2) + r;
            if (pxl < 56) {
                float v = fmaxf(acc[n][r] + bo, 0.f);
                h_g[((size_t)b * HW + px0 + pxl) * 64 + o] = (ushort_t)f2bf(v);
            }
        }
    }
}

// k2: fused weight-GEMM (bf16 MFMA) + involution. 1792 blocks, XCD-chunked decode.
__global__ __launch_bounds__(256, 5) void k2_fused(
        const float* __restrict__ x, const ushort_t* __restrict__ h_g,
        const float* __restrict__ w2, const float* __restrict__ b2,
        float* __restrict__ out) {
    __shared__ __align__(16) char lds[LDS_TOT];
    // XCD-chunked bijective decode: each XCD gets contiguous (b, tile-chunk, g) span
    int wid = blockIdx.x;
    int xcd = wid & 7, pos = wid >> 3;
    int work = xcd * 224 + pos;
    int b = work / 448;
    int r0 = work % 448;
    int tchunk = r0 >> 6, r2 = r0 & 63;
    int g = r2 >> 2;
    int tile = (tchunk << 2) + (r2 & 3);
    int tid = threadIdx.x;

    // ---- Phase A1: stage h tile (112 px rows x 64c bf16), XOR-swizzled rows ----
    const char* hg = (const char*)h_g + ((size_t)b * HW + tile * 112) * 128;
    for (int i = tid; i < 896; i += 256) {          // 896 x 16B chunks
        int row = i >> 3, cb = (i & 7) << 4;
        u32x4 v = *(const u32x4*)(hg + row * 128 + cb);
        *(u32x4*)(lds + row * 128 + (cb ^ ((row & 7) << 4))) = v;
    }
    // ---- Phase A2: w2 group -> bf16, rows padded to 64 taps, swizzled ----
    {
        int k = tid >> 2, cg = tid & 3;
        unsigned int pk[8];
        if (k < 49) {
            const float* wr = w2 + ((size_t)(g * 49 + k)) * 64 + cg * 16;
#pragma unroll
            for (int i = 0; i < 8; i++)
                pk[i] = f2bf(wr[2 * i]) | (f2bf(wr[2 * i + 1]) << 16);
        } else {
#pragma unroll
            for (int i = 0; i < 8; i++) pk[i] = 0;
        }
#pragma unroll
        for (int hh = 0; hh < 2; hh++) {
            u32x4 v = {pk[hh * 4 + 0], pk[hh * 4 + 1], pk[hh * 4 + 2], pk[hh * 4 + 3]};
            *(u32x4*)(lds + LDS_W2P + k * 128 + ((cg * 32 + hh * 16) ^ ((k & 7) << 4))) = v;
        }
    }
    if (tid < 49) ((float*)(lds + LDS_B2S))[tid] = b2[g * 49 + tid];
    __syncthreads();

    // ---- Phase B: wgt[64tap][112px] = w2p(64x64) @ h(64c x 112px) via MFMA ----
    int lane = tid & 63, wd = tid >> 6;
    f32x4 acc[7];
#pragma unroll
    for (int n = 0; n < 7; n++) acc[n] = (f32x4){0.f, 0.f, 0.f, 0.f};
    int arow = wd * 16 + (lane & 15);
#pragma unroll
    for (int ks = 0; ks < 2; ks++) {
        int kc = ks * 64 + ((lane >> 4) << 4);       // byte col of 8 bf16 k-chunk
        short8 a = *(const short8*)(lds + LDS_W2P + arow * 128 + (kc ^ ((arow & 7) << 4)));
#pragma unroll
        for (int n = 0; n < 7; n++) {
            int brow = n * 16 + (lane & 15);
            short8 bb = *(const short8*)(lds + brow * 128 + (kc ^ ((brow & 7) << 4)));
            acc[n] = __builtin_amdgcn_mfma_f32_16x16x32_bf16(a, bb, acc[n], 0, 0, 0);
        }
    }
    __syncthreads();    // all B-reads done before overwriting h_t/w2p with wgt

    // ---- Epilogue: wgt fp32 [64][116] at lds+0 (aliases h_t/w2p), +bias ----
    {
        const float* b2s = (const float*)(lds + LDS_B2S);
#pragma unroll
        for (int n = 0; n < 7; n++) {
#pragma unroll
            for (int rr = 0; rr < 4; rr++) {
                int tap = wd * 16 + ((lane >> 4) << 2) + rr;
                if (tap < 49) {
                    int px = n * 16 + (lane & 15);
                    ((float*)lds)[tap * 116 + px] = acc[n][rr] + b2s[tap];
                }
            }
        }
    }
    __syncthreads();

    // ---- Phase D: involution. thread = (2 channels, 4 contiguous px) ----
    int cq = tid >> 5, pg = tid & 31;
    if (pg < 28) {
        int py = (pg >= 14) ? 1 : 0;
        int x0 = (pg - 14 * py) * 4;               // col of first px in row
        int c0 = g * 16 + cq * 2;
        int rowb = tile * 2 + py;
        float accd[2][4] = {{0.f, 0.f, 0.f, 0.f}, {0.f, 0.f, 0.f, 0.f}};
        for (int ky = 0; ky < 7; ky++) {
            int rr = rowb + ky - 3;
            if (rr < 0 || rr >= 56) continue;      // zero-pad rows contribute 0
            float w[2][12];
#pragma unroll
            for (int cc = 0; cc < 2; cc++) {
                int base = (b * 256 + c0 + cc) * HW + rr * 56 + x0 - 4;
#pragma unroll
                for (int k3 = 0; k3 < 3; k3++) {
                    int o = base + k3 * 4;
                    o = min(max(o, 0), NX - 4);    // clamp: OOB values get zeroed below
                    *(f32x4*)&w[cc][k3 * 4] = *(const f32x4*)(x + o);
                }
            }
            if (x0 == 0) {                          // img cols < 0
                w[0][1] = w[0][2] = w[0][3] = 0.f;
                w[1][1] = w[1][2] = w[1][3] = 0.f;
            }
            if (x0 == 52) {                         // img cols > 55
                w[0][8] = w[0][9] = w[0][10] = 0.f;
                w[1][8] = w[1][9] = w[1][10] = 0.f;
            }
#pragma unroll
            for (int kx = 0; kx < 7; kx++) {
                f32x4 wg = *(const f32x4*)(lds + ((ky * 7 + kx) * 116 + py * 56 + x0) * 4);
#pragma unroll
                for (int cc = 0; cc < 2; cc++) {
#pragma unroll
                    for (int pi = 0; pi < 4; pi++)
                        accd[cc][pi] = fmaf(wg[pi], w[cc][pi + kx + 1], accd[cc][pi]);
                }
            }
        }
#pragma unroll
        for (int cc = 0; cc < 2; cc++) {
            f32x4 st = {accd[cc][0], accd[cc][1], accd[cc][2], accd[cc][3]};
            *(f32x4*)(out + (size_t)(b * 256 + c0 + cc) * HW + tile * 112 + pg * 4) = st;
        }
    }
}

extern "C" void kernel_launch(void* const* d_in, const int* in_sizes, int n_in,
                              void* d_out, int out_size, void* d_ws, size_t ws_size,
                              hipStream_t stream) {
    const float* x     = (const float*)d_in[0];
    const float* w1    = (const float*)d_in[1];
    const float* gamma = (const float*)d_in[2];
    const float* beta  = (const float*)d_in[3];
    const float* mean  = (const float*)d_in[4];
    const float* var   = (const float*)d_in[5];
    const float* w2    = (const float*)d_in[6];
    const float* b2    = (const float*)d_in[7];
    float* out = (float*)d_out;

    ushort_t* w1bf  = (ushort_t*)d_ws;                             // 32 KB bf16
    float* bias_d   = (float*)((char*)d_ws + 32768);               // 256 B
    ushort_t* h_g   = (ushort_t*)((char*)d_ws + 36864);            // 1.6 MB bf16

    k0_prep<<<64, 256, 0, stream>>>(w1, gamma, beta, mean, var, w1bf, bias_d);
    k1_mfma<<<224, 256, 0, stream>>>(x, w1bf, bias_d, h_g);
    k2_fused<<<1792, 256, 0, stream>>>(x, h_g, w2, b2, out);
}

// Round 5
// 35.002 us; speedup vs baseline: 3.3162x; 1.1362x over previous
//
#include <hip/hip_runtime.h>

typedef __attribute__((ext_vector_type(8))) short short8;
typedef __attribute__((ext_vector_type(4))) float f32x4;
typedef __attribute__((ext_vector_type(4))) unsigned int u32x4;
typedef unsigned short ushort_t;

#define BB 4
#define HW 3136
#define NX (4*256*3136)          // total x elements

// k1 LDS regions
#define K1_XB0 32768
#define K1_XB1 36864
#define K1_BIAS 40960
#define K1_SCV 41216
#define K1_TOT 41472

// k2 LDS regions (4-row tile): h 224*128 @0, w2p @28672, bias @36864
// wgt bf16 [64][232] @0 (aliases h+w2p after phase B)
#define K2_W2P 28672
#define K2_B2S 36864
#define K2_TOT 37120

__device__ __forceinline__ unsigned int f2bf(float f) {
    unsigned int u = __float_as_uint(f);
    return (u + 0x7FFFu + ((u >> 16) & 1u)) >> 16;   // RNE to bf16 bits
}

// k1: h = relu(conv1+bn) via bf16 MFMA, BN fold fused into w1 staging.
// h_g[b][px][64c] bf16. Block = 56-px tile, 4 waves. M=56(pad64) N=64o K=256c.
__global__ __launch_bounds__(256) void k1_mfma(
        const float* __restrict__ x, const float* __restrict__ w1,
        const float* __restrict__ gamma, const float* __restrict__ beta,
        const float* __restrict__ mean, const float* __restrict__ var,
        ushort_t* __restrict__ h_g) {
    __shared__ __align__(16) char lds[K1_TOT];
    int blk = blockIdx.x;
    int tile = blk % 56, b = blk / 56;
    int px0 = tile * 56;
    int tid = threadIdx.x;
    int lane = tid & 63, w = tid >> 6;

    // x staging: thread -> (px = tid&63, cg = tid>>6), 8 c each; issue step0 early
    int spx = tid & 63, scg = tid >> 6;
    int gpx = min(px0 + spx, HW - 1);              // clamp pad rows (masked later)
    const float* xbase = x + (size_t)b * 256 * HW + gpx;
    int sdst_off = spx * 64 + ((scg << 4) ^ ((spx & 3) << 4));

    float xr[8];
#pragma unroll
    for (int u = 0; u < 8; u++) xr[u] = xbase[(size_t)(scg * 8 + u) * HW];

    // BN fold vectors
    if (tid < 64) {
        float sc = gamma[tid] * rsqrtf(var[tid] + 1e-5f);
        ((float*)(lds + K1_SCV))[tid] = sc;
        ((float*)(lds + K1_BIAS))[tid] = beta[tid] - mean[tid] * sc;
    }
    __syncthreads();

    // stage w1 [64o][256c] -> bf16*scale, rows 512B, XOR-swizzled
    for (int i = tid; i < 2048; i += 256) {        // 16B bf16 chunks
        int row = i >> 5, col8 = i & 31;
        const float* src = w1 + row * 256 + col8 * 8;
        f32x4 a = *(const f32x4*)src;
        f32x4 c = *(const f32x4*)(src + 4);
        float sc = ((const float*)(lds + K1_SCV))[row];
        unsigned int pk[4];
        pk[0] = f2bf(a[0] * sc) | (f2bf(a[1] * sc) << 16);
        pk[1] = f2bf(a[2] * sc) | (f2bf(a[3] * sc) << 16);
        pk[2] = f2bf(c[0] * sc) | (f2bf(c[1] * sc) << 16);
        pk[3] = f2bf(c[2] * sc) | (f2bf(c[3] * sc) << 16);
        u32x4 v = {pk[0], pk[1], pk[2], pk[3]};
        *(u32x4*)(lds + (row << 9) + ((col8 << 4) ^ ((row & 7) << 4))) = v;
    }

    f32x4 acc[4];
#pragma unroll
    for (int n = 0; n < 4; n++) acc[n] = (f32x4){0.f, 0.f, 0.f, 0.f};

    // write x step0
    {
        unsigned int pk[4];
#pragma unroll
        for (int j = 0; j < 4; j++)
            pk[j] = f2bf(xr[2 * j]) | (f2bf(xr[2 * j + 1]) << 16);
        u32x4 v = {pk[0], pk[1], pk[2], pk[3]};
        *(u32x4*)(lds + K1_XB0 + sdst_off) = v;
    }
    __syncthreads();

    int arow = w * 16 + (lane & 15);
    int a_off = arow * 64 + (((lane >> 4) << 4) ^ ((arow & 3) << 4));

    for (int ks = 0; ks < 8; ks++) {
        if (ks < 7) {
            const float* xp = xbase + (size_t)((ks + 1) * 32 + scg * 8) * HW;
#pragma unroll
            for (int u = 0; u < 8; u++) xr[u] = xp[(size_t)u * HW];
        }
        int xb = (ks & 1) ? K1_XB1 : K1_XB0;
        short8 a = *(const short8*)(lds + xb + a_off);
#pragma unroll
        for (int n = 0; n < 4; n++) {
            int brow = n * 16 + (lane & 15);
            short8 bb = *(const short8*)(lds + (brow << 9) +
                          ((ks * 64 + ((lane >> 4) << 4)) ^ ((brow & 7) << 4)));
            acc[n] = __builtin_amdgcn_mfma_f32_16x16x32_bf16(a, bb, acc[n], 0, 0, 0);
        }
        __syncthreads();
        if (ks < 7) {
            unsigned int pk[4];
#pragma unroll
            for (int j = 0; j < 4; j++)
                pk[j] = f2bf(xr[2 * j]) | (f2bf(xr[2 * j + 1]) << 16);
            u32x4 v = {pk[0], pk[1], pk[2], pk[3]};
            *(u32x4*)(lds + ((ks & 1) ? K1_XB0 : K1_XB1) + sdst_off) = v;
            __syncthreads();
        }
    }

    // epilogue: h_g[(b*HW+px)*64 + o] = relu(acc + bias)
#pragma unroll
    for (int n = 0; n < 4; n++) {
        int o = n * 16 + (lane & 15);
        float bo = ((const float*)(lds + K1_BIAS))[o];
#pragma unroll
        for (int r = 0; r < 4; r++) {
            int pxl = w * 16 + ((lane >> 4) << 2) + r;
            if (pxl < 56) {
                float v = fmaxf(acc[n][r] + bo, 0.f);
                h_g[((size_t)b * HW + px0 + pxl) * 64 + o] = (ushort_t)f2bf(v);
            }
        }
    }
}

// k2: fused weight-GEMM (bf16 MFMA) + involution.
// 4-row tile (224 px), 896 blocks, 256 threads, XCD-chunked decode.
__global__ __launch_bounds__(256, 4) void k2_fused(
        const float* __restrict__ x, const ushort_t* __restrict__ h_g,
        const float* __restrict__ w2, const float* __restrict__ b2,
        float* __restrict__ out) {
    __shared__ __align__(16) char lds[K2_TOT];
    // bijective XCD decode: 896 = 8 xcd * 112; per-XCD span = half-batch, 7 tiles, all g
    int wid0 = blockIdx.x;
    int xcd = wid0 & 7, pos = wid0 >> 3;
    int work = xcd * 112 + pos;
    int b = work / 224;
    int rem = work - b * 224;
    int half = rem / 112, r2 = rem - half * 112;
    int tloc = r2 >> 4, g = r2 & 15;
    int tile = half * 7 + tloc;                    // 0..13, rows [tile*4, tile*4+4)
    int tid = threadIdx.x;

    // ---- Phase A1: stage h tile (224 px rows x 64c bf16), XOR-swizzled ----
    const char* hg = (const char*)h_g + ((size_t)b * HW + tile * 224) * 128;
    for (int i = tid; i < 1792; i += 256) {        // 16B chunks
        int row = i >> 3, cb = (i & 7) << 4;
        u32x4 v = *(const u32x4*)(hg + row * 128 + cb);
        *(u32x4*)(lds + row * 128 + (cb ^ ((row & 7) << 4))) = v;
    }
    // ---- Phase A2: w2 group -> bf16, rows padded to 64 taps, swizzled ----
    {
        int k = tid >> 2, cg = tid & 3;
        unsigned int pk[8];
        if (k < 49) {
            const float* wr = w2 + ((size_t)(g * 49 + k)) * 64 + cg * 16;
#pragma unroll
            for (int i = 0; i < 8; i++)
                pk[i] = f2bf(wr[2 * i]) | (f2bf(wr[2 * i + 1]) << 16);
        } else {
#pragma unroll
            for (int i = 0; i < 8; i++) pk[i] = 0;
        }
#pragma unroll
        for (int hh = 0; hh < 2; hh++) {
            u32x4 v = {pk[hh * 4 + 0], pk[hh * 4 + 1], pk[hh * 4 + 2], pk[hh * 4 + 3]};
            *(u32x4*)(lds + K2_W2P + k * 128 + ((cg * 32 + hh * 16) ^ ((k & 7) << 4))) = v;
        }
    }
    if (tid < 49) ((float*)(lds + K2_B2S))[tid] = b2[g * 49 + tid];
    __syncthreads();

    // ---- Phase B: wgt[64tap][224px] = w2p(64x64) @ h(64c x 224px) via MFMA ----
    int lane = tid & 63, wd = tid >> 6;
    f32x4 acc[14];
#pragma unroll
    for (int n = 0; n < 14; n++) acc[n] = (f32x4){0.f, 0.f, 0.f, 0.f};
    int arow = wd * 16 + (lane & 15);
#pragma unroll
    for (int ks = 0; ks < 2; ks++) {
        int kc = ks * 64 + ((lane >> 4) << 4);       // byte col of 8 bf16 k-chunk
        short8 a = *(const short8*)(lds + K2_W2P + arow * 128 + (kc ^ ((arow & 7) << 4)));
#pragma unroll
        for (int n = 0; n < 14; n++) {
            int brow = n * 16 + (lane & 15);
            short8 bb = *(const short8*)(lds + brow * 128 + (kc ^ ((brow & 7) << 4)));
            acc[n] = __builtin_amdgcn_mfma_f32_16x16x32_bf16(a, bb, acc[n], 0, 0, 0);
        }
    }
    __syncthreads();    // all B-reads done before overwriting h_t/w2p with wgt

    // ---- Epilogue: wgt bf16 [64][232] @0 (aliases h/w2p), +bias ----
    {
        const float* b2s = (const float*)(lds + K2_B2S);
        ushort_t* wl = (ushort_t*)lds;
#pragma unroll
        for (int n = 0; n < 14; n++) {
#pragma unroll
            for (int rr = 0; rr < 4; rr++) {
                int tap = wd * 16 + ((lane >> 4) << 2) + rr;
                if (tap < 49) {
                    int px = n * 16 + (lane & 15);
                    wl[tap * 232 + px] = (ushort_t)f2bf(acc[n][rr] + b2s[tap]);
                }
            }
        }
    }
    __syncthreads();

    // ---- Phase D: involution. thread = (2 channels, 8 contiguous px) ----
    int cpk = tid >> 5;            // 0..7 channel-pair
    int pg = tid & 31;
    int py = pg >> 3, xi = pg & 7; // 4 rows x 7 octets (xi<7 active)
    if (xi < 7) {
        int x0 = xi * 8;
        int c0 = g * 16 + cpk * 2;
        int rowb = tile * 4 + py;
        float accd[2][8];
#pragma unroll
        for (int cc = 0; cc < 2; cc++)
#pragma unroll
            for (int pi = 0; pi < 8; pi++) accd[cc][pi] = 0.f;

        for (int ky = 0; ky < 7; ky++) {
            int rr = rowb + ky - 3;
            if (rr < 0 || rr >= 56) continue;      // zero-pad rows contribute 0
            float w[2][16];
#pragma unroll
            for (int cc = 0; cc < 2; cc++) {
                int base = (b * 256 + c0 + cc) * HW + rr * 56 + x0 - 4;
#pragma unroll
                for (int k4 = 0; k4 < 4; k4++) {
                    int o = base + k4 * 4;
                    o = min(max(o, 0), NX - 4);    // clamp; OOB values zeroed below
                    *(f32x4*)&w[cc][k4 * 4] = *(const f32x4*)(x + o);
                }
            }
            if (x0 == 0) {                          // img cols < 0
#pragma unroll
                for (int cc = 0; cc < 2; cc++) { w[cc][1] = w[cc][2] = w[cc][3] = 0.f; }
            }
            if (x0 == 48) {                         // img cols > 55
#pragma unroll
                for (int cc = 0; cc < 2; cc++) { w[cc][12] = w[cc][13] = w[cc][14] = 0.f; }
            }
#pragma unroll
            for (int kx = 0; kx < 7; kx++) {
                // 8 bf16 weights for px x0..x0+7 of tap (ky,kx)
                u32x4 wv = *(const u32x4*)(lds + ((ky * 7 + kx) * 232 + py * 56 + x0) * 2);
                float wf[8];
#pragma unroll
                for (int j = 0; j < 4; j++) {
                    wf[2 * j]     = __uint_as_float(wv[j] << 16);
                    wf[2 * j + 1] = __uint_as_float(wv[j] & 0xFFFF0000u);
                }
#pragma unroll
                for (int cc = 0; cc < 2; cc++)
#pragma unroll
                    for (int pi = 0; pi < 8; pi++)
                        accd[cc][pi] = fmaf(wf[pi], w[cc][pi + kx + 1], accd[cc][pi]);
            }
        }
#pragma unroll
        for (int cc = 0; cc < 2; cc++) {
            float* op = out + (size_t)(b * 256 + c0 + cc) * HW + tile * 224 + py * 56 + x0;
            *(f32x4*)op = (f32x4){accd[cc][0], accd[cc][1], accd[cc][2], accd[cc][3]};
            *(f32x4*)(op + 4) = (f32x4){accd[cc][4], accd[cc][5], accd[cc][6], accd[cc][7]};
        }
    }
}

extern "C" void kernel_launch(void* const* d_in, const int* in_sizes, int n_in,
                              void* d_out, int out_size, void* d_ws, size_t ws_size,
                              hipStream_t stream) {
    const float* x     = (const float*)d_in[0];
    const float* w1    = (const float*)d_in[1];
    const float* gamma = (const float*)d_in[2];
    const float* beta  = (const float*)d_in[3];
    const float* mean  = (const float*)d_in[4];
    const float* var   = (const float*)d_in[5];
    const float* w2    = (const float*)d_in[6];
    const float* b2    = (const float*)d_in[7];
    float* out = (float*)d_out;

    ushort_t* h_g = (ushort_t*)d_ws;               // [B][3136][64] bf16 = 1.6 MB

    k1_mfma<<<224, 256, 0, stream>>>(x, w1, gamma, beta, mean, var, h_g);
    k2_fused<<<896, 256, 0, stream>>>(x, h_g, w2, b2, out);
}